// Round 2
// baseline (434.506 us; speedup 1.0000x reference)
//
#include <hip/hip_runtime.h>
#include <hip/hip_bf16.h>

// Problem constants (B,S,E,H,D) = (4,2048,1024,16,64)
#define PB 4
#define PS 2048
#define PE 1024
#define PH 16
#define PD 64

typedef __attribute__((ext_vector_type(8))) short bf16x8;
typedef __attribute__((ext_vector_type(4))) float f32x4;
typedef __attribute__((ext_vector_type(4))) unsigned int u32x4;

__device__ __forceinline__ unsigned short f2bf(float f) {
  union { float f; unsigned int u; } v;
  v.f = f;
  unsigned int u = v.u;
  u += 0x7fffu + ((u >> 16) & 1u);  // RNE
  return (unsigned short)(u >> 16);
}

__device__ __forceinline__ f32x4 mfma16(bf16x8 a, bf16x8 b, f32x4 c) {
  return __builtin_amdgcn_mfma_f32_16x16x32_bf16(a, b, c, 0, 0, 0);
}

// ---------------- fp32 -> bf16 conversion (x, Wk, Wq, Wo fused) --------------
// total float4 groups = (B*S*E + 3*E*E)/4 = 2883584; one group per thread.
#define CVT_GROUPS ((PB * PS * PE + 3 * PE * PE) / 4)
#define CVT_BLOCKS (CVT_GROUPS / 256)   // 11264
__global__ __launch_bounds__(256) void cvt_kernel(
    const float* __restrict__ x, const float* __restrict__ wk,
    const float* __restrict__ wq, const float* __restrict__ wo,
    unsigned short* __restrict__ xb, unsigned short* __restrict__ wkb,
    unsigned short* __restrict__ wqb, unsigned short* __restrict__ wob) {
  const long long NX = (long long)PB * PS * PE;   // 8388608
  const long long NW = (long long)PE * PE;        // 1048576
  long long i = ((long long)blockIdx.x * 256 + threadIdx.x) * 4;
  const float* src;
  unsigned short* dst;
  long long off;
  if (i < NX)               { src = x;  dst = xb;  off = i; }
  else if (i < NX + NW)     { src = wk; dst = wkb; off = i - NX; }
  else if (i < NX + 2 * NW) { src = wq; dst = wqb; off = i - NX - NW; }
  else                      { src = wo; dst = wob; off = i - NX - 2 * NW; }
  float4 v = *(const float4*)(src + off);
  ushort4 o;
  o.x = f2bf(v.x); o.y = f2bf(v.y); o.z = f2bf(v.z); o.w = f2bf(v.w);
  *(ushort4*)(dst + off) = o;
}

// ---------------- NT bf16 GEMM: C[M,N] = A[M,K] * B[N,K]^T (+bias) -----------
// 128x128 tile, BK=32, 4 waves each computing 64x64 via 4x4 of 16x16x32 MFMA.
template <int ADD_BIAS, int OUT_BF16>
__global__ __launch_bounds__(256) void gemm_nt(
    const unsigned short* __restrict__ A, const unsigned short* __restrict__ Bm,
    const float* __restrict__ bias, float* __restrict__ Cf,
    unsigned short* __restrict__ Cb, int M, int N, int K) {
  __shared__ __attribute__((aligned(16))) unsigned short As[128 * 32];
  __shared__ __attribute__((aligned(16))) unsigned short Bs[128 * 32];
  const int tid = threadIdx.x;
  const int wave = tid >> 6, lane = tid & 63;
  const int quad = lane >> 4, ln = lane & 15;
  const int m0 = blockIdx.y * 128, n0 = blockIdx.x * 128;
  const int wm = (wave >> 1) * 64, wn = (wave & 1) * 64;
  const int sr = tid >> 2, sq = tid & 3;  // staging: row 0..63 (+64), 16B chunk

  f32x4 acc[4][4];
#pragma unroll
  for (int i = 0; i < 4; ++i)
#pragma unroll
    for (int j = 0; j < 4; ++j)
#pragma unroll
      for (int r = 0; r < 4; ++r) acc[i][j][r] = 0.f;

  for (int k0 = 0; k0 < K; k0 += 32) {
    u32x4 a0 = *(const u32x4*)(A + (size_t)(m0 + sr) * K + k0 + sq * 8);
    u32x4 a1 = *(const u32x4*)(A + (size_t)(m0 + sr + 64) * K + k0 + sq * 8);
    u32x4 b0 = *(const u32x4*)(Bm + (size_t)(n0 + sr) * K + k0 + sq * 8);
    u32x4 b1 = *(const u32x4*)(Bm + (size_t)(n0 + sr + 64) * K + k0 + sq * 8);
    *(u32x4*)(As + sr * 32 + sq * 8) = a0;
    *(u32x4*)(As + (sr + 64) * 32 + sq * 8) = a1;
    *(u32x4*)(Bs + sr * 32 + sq * 8) = b0;
    *(u32x4*)(Bs + (sr + 64) * 32 + sq * 8) = b1;
    __syncthreads();
    bf16x8 af[4], bfr[4];
#pragma unroll
    for (int t = 0; t < 4; ++t) {
      af[t]  = *(const bf16x8*)(As + (wm + t * 16 + ln) * 32 + quad * 8);
      bfr[t] = *(const bf16x8*)(Bs + (wn + t * 16 + ln) * 32 + quad * 8);
    }
#pragma unroll
    for (int mt = 0; mt < 4; ++mt)
#pragma unroll
      for (int nt = 0; nt < 4; ++nt)
        acc[mt][nt] = mfma16(af[mt], bfr[nt], acc[mt][nt]);
    __syncthreads();
  }

#pragma unroll
  for (int mt = 0; mt < 4; ++mt) {
#pragma unroll
    for (int nt = 0; nt < 4; ++nt) {
      const int row = m0 + wm + mt * 16 + quad * 4;
      const int col = n0 + wn + nt * 16 + ln;
      float bv = 0.f;
      if (ADD_BIAS) bv = bias[col];
#pragma unroll
      for (int r = 0; r < 4; ++r) {
        float v = acc[mt][nt][r] + bv;
        if (OUT_BF16) Cb[(size_t)(row + r) * N + col] = f2bf(v);
        else          Cf[(size_t)(row + r) * N + col] = v;
      }
    }
  }
}

// ---------------- fused causal attention, V == Q (reference bug) -------------
// 1 block = (b, h, 64-query tile); 4 waves x 16 query rows; flash-style online
// softmax; score scale = 1/sqrt(E) = 1/32.
__global__ __launch_bounds__(256) void attn_kernel(
    const unsigned short* __restrict__ Qb, const unsigned short* __restrict__ Kb,
    unsigned short* __restrict__ Ab) {
  __shared__ __attribute__((aligned(16))) unsigned short Ks[64 * 72];      // [kk][d]
  __shared__ __attribute__((aligned(16))) unsigned short Vs[64 * 72];      // [d][kk] xor-swizzled
  __shared__ __attribute__((aligned(16))) unsigned short Ps[4][16 * 72];   // per-wave P

  const int tid = threadIdx.x;
  const int wave = tid >> 6, lane = tid & 63;
  const int quad = lane >> 4, ln = lane & 15;
  const int qt = blockIdx.x, h = blockIdx.y, b = blockIdx.z;
  const int q0 = qt * 64;
  const int qw0 = q0 + wave * 16;
  const size_t hoff = ((size_t)b * PS) * PE + (size_t)h * PD;
  const int sr = tid >> 3, sp = tid & 7;  // staging: row 0..31 (+32), 8-elem part

  // Q fragments (A-layout) for this wave's 16 rows, kept in regs all kernel
  bf16x8 qf[2];
#pragma unroll
  for (int c = 0; c < 2; ++c)
    qf[c] = *(const bf16x8*)(Qb + hoff + (size_t)(qw0 + ln) * PE + c * 32 + quad * 8);

  f32x4 o[4];
  float mrow[4], lrow[4];
#pragma unroll
  for (int t = 0; t < 4; ++t)
#pragma unroll
    for (int r = 0; r < 4; ++r) o[t][r] = 0.f;
#pragma unroll
  for (int r = 0; r < 4; ++r) { mrow[r] = -1e30f; lrow[r] = 0.f; }

  for (int kt = 0; kt <= qt; ++kt) {
    const int k0 = kt * 64;
    // stage K tile row-major; stage V(=Q) tile transposed with xor-swizzle
#pragma unroll
    for (int half = 0; half < 2; ++half) {
      const int row = sr + half * 32;
      u32x4 kv = *(const u32x4*)(Kb + hoff + (size_t)(k0 + row) * PE + sp * 8);
      *(u32x4*)(Ks + row * 72 + sp * 8) = kv;
      u32x4 qv = *(const u32x4*)(Qb + hoff + (size_t)(k0 + row) * PE + sp * 8);
      unsigned short tmp[8];
      *(u32x4*)tmp = qv;
      const int swz = ((row >> 3) ^ sp) << 3;
#pragma unroll
      for (int j = 0; j < 8; ++j)
        Vs[(sp * 8 + j) * 72 + swz + (row & 7)] = tmp[j];
    }
    __syncthreads();

    // S = Q K^T  (rows=queries, cols=keys)
    f32x4 sacc[4];
#pragma unroll
    for (int nt = 0; nt < 4; ++nt)
#pragma unroll
      for (int r = 0; r < 4; ++r) sacc[nt][r] = 0.f;
#pragma unroll
    for (int c = 0; c < 2; ++c)
#pragma unroll
      for (int nt = 0; nt < 4; ++nt) {
        bf16x8 kf = *(const bf16x8*)(Ks + (nt * 16 + ln) * 72 + c * 32 + quad * 8);
        sacc[nt] = mfma16(qf[c], kf, sacc[nt]);
      }

    // scale + causal mask + row max (C-layout: row = quad*4+r, col = ln)
    float rmax[4];
#pragma unroll
    for (int r = 0; r < 4; ++r) rmax[r] = -1e30f;
#pragma unroll
    for (int nt = 0; nt < 4; ++nt) {
      const int kg = k0 + nt * 16 + ln;
#pragma unroll
      for (int r = 0; r < 4; ++r) {
        const int qg = qw0 + quad * 4 + r;
        float s = sacc[nt][r] * 0.03125f;
        s = (kg <= qg) ? s : -1e30f;
        sacc[nt][r] = s;
        rmax[r] = fmaxf(rmax[r], s);
      }
    }
#pragma unroll
    for (int msk = 1; msk < 16; msk <<= 1)
#pragma unroll
      for (int r = 0; r < 4; ++r)
        rmax[r] = fmaxf(rmax[r], __shfl_xor(rmax[r], msk, 64));

    float alpha[4], psum[4];
#pragma unroll
    for (int r = 0; r < 4; ++r) {
      const float mn = fmaxf(mrow[r], rmax[r]);
      alpha[r] = __expf(mrow[r] - mn);
      mrow[r] = mn;
      psum[r] = 0.f;
    }
#pragma unroll
    for (int nt = 0; nt < 4; ++nt)
#pragma unroll
      for (int r = 0; r < 4; ++r) {
        const float p = __expf(sacc[nt][r] - mrow[r]);
        psum[r] += p;
        Ps[wave][(quad * 4 + r) * 72 + nt * 16 + ln] = f2bf(p);
      }
#pragma unroll
    for (int msk = 1; msk < 16; msk <<= 1)
#pragma unroll
      for (int r = 0; r < 4; ++r) psum[r] += __shfl_xor(psum[r], msk, 64);
#pragma unroll
    for (int r = 0; r < 4; ++r) lrow[r] = lrow[r] * alpha[r] + psum[r];
#pragma unroll
    for (int t = 0; t < 4; ++t)
#pragma unroll
      for (int r = 0; r < 4; ++r) o[t][r] *= alpha[r];

    // O += P V   (P via LDS round-trip into A-layout; V from swizzled Vs)
#pragma unroll
    for (int c = 0; c < 2; ++c) {
      bf16x8 pf = *(const bf16x8*)(&Ps[wave][ln * 72 + c * 32 + quad * 8]);
#pragma unroll
      for (int t = 0; t < 4; ++t) {
        const int d = t * 16 + ln;
        const int swz = ((c * 4 + quad) ^ (t * 2 + (ln >> 3))) << 3;
        bf16x8 vf = *(const bf16x8*)(Vs + d * 72 + swz);
        o[t] = mfma16(pf, vf, o[t]);
      }
    }
    __syncthreads();
  }

  // epilogue: normalize and store bf16
#pragma unroll
  for (int t = 0; t < 4; ++t) {
#pragma unroll
    for (int r = 0; r < 4; ++r) {
      const int qg = qw0 + quad * 4 + r;
      Ab[hoff + (size_t)qg * PE + t * 16 + ln] = f2bf(o[t][r] / lrow[r]);
    }
  }
}

// ---------------------------------------------------------------------------
extern "C" void kernel_launch(void* const* d_in, const int* in_sizes, int n_in,
                              void* d_out, int out_size, void* d_ws, size_t ws_size,
                              hipStream_t stream) {
  (void)in_sizes; (void)n_in; (void)out_size; (void)ws_size;
  const float* x  = (const float*)d_in[0];
  const float* Wk = (const float*)d_in[1];
  const float* Wq = (const float*)d_in[2];
  // d_in[3] = Wv : dead in the reference (V = Q bug) — never touched.
  const float* Wo = (const float*)d_in[4];
  const float* bo = (const float*)d_in[5];
  float* out = (float*)d_out;

  // workspace layout (bytes); Ab aliases xb (xb consumed by the two GEMMs
  // which complete before attn writes Ab — stream-ordered).
  char* ws = (char*)d_ws;
  unsigned short* xb  = (unsigned short*)(ws);                       // 16 MiB
  unsigned short* wkb = (unsigned short*)(ws + (16u << 20));         //  2 MiB
  unsigned short* wqb = (unsigned short*)(ws + (18u << 20));         //  2 MiB
  unsigned short* wob = (unsigned short*)(ws + (20u << 20));         //  2 MiB
  unsigned short* Qb  = (unsigned short*)(ws + (22u << 20));         // 16 MiB
  unsigned short* Kb  = (unsigned short*)(ws + (38u << 20));         // 16 MiB
  unsigned short* Ab  = xb;                                          // alias

  const int M = PB * PS;  // 8192

  // 1) convert inputs to bf16 — ONE THREAD PER float4 GROUP (11264 blocks;
  //    round-1 bug: under-launched by 4x and left ws poisoned).
  cvt_kernel<<<dim3(CVT_BLOCKS), dim3(256), 0, stream>>>(
      x, Wk, Wq, Wo, xb, wkb, wqb, wob);

  // 2) Q = x Wq^T ; K = x Wk^T   (bf16 out)
  gemm_nt<0, 1><<<dim3(PE / 128, M / 128), dim3(256), 0, stream>>>(
      xb, wqb, nullptr, nullptr, Qb, M, PE, PE);
  gemm_nt<0, 1><<<dim3(PE / 128, M / 128), dim3(256), 0, stream>>>(
      xb, wkb, nullptr, nullptr, Kb, M, PE, PE);

  // 3) causal attention (V = Q), scale 1/32
  attn_kernel<<<dim3(PS / 64, PH, PB), dim3(256), 0, stream>>>(Qb, Kb, Ab);

  // 4) out = attn Wo^T + bo   (fp32 out)
  gemm_nt<1, 0><<<dim3(PE / 128, M / 128), dim3(256), 0, stream>>>(
      Ab, wob, bo, out, nullptr, M, PE, PE);
}